// Round 8
// baseline (622.006 us; speedup 1.0000x reference)
//
#include <hip/hip_runtime.h>
#include <hip/hip_bf16.h>

#define N_NODES 50000
#define N_EDGES 800000
#define HID 64

__device__ __forceinline__ unsigned short f2bf(float f) {
    union { float f; unsigned int i; } v;
    v.f = f;
    unsigned int b = v.i;
    return (unsigned short)((b + 0x7FFFu + ((b >> 16) & 1u)) >> 16);
}

// add a 64-wide bf16 row into x[64]
__device__ __forceinline__ void add_bf16_row(float* x, const unsigned short* row) {
    const uint4* r4 = (const uint4*)row;
#pragma unroll
    for (int q = 0; q < 8; ++q) {
        uint4 v = r4[q];
        union { unsigned int i; float f; } t;
        t.i = v.x << 16;         x[q*8 + 0] += t.f;
        t.i = v.x & 0xFFFF0000u; x[q*8 + 1] += t.f;
        t.i = v.y << 16;         x[q*8 + 2] += t.f;
        t.i = v.y & 0xFFFF0000u; x[q*8 + 3] += t.f;
        t.i = v.z << 16;         x[q*8 + 4] += t.f;
        t.i = v.z & 0xFFFF0000u; x[q*8 + 5] += t.f;
        t.i = v.w << 16;         x[q*8 + 6] += t.f;
        t.i = v.w & 0xFFFF0000u; x[q*8 + 7] += t.f;
    }
}

// ---------------- CSR build ----------------

__global__ void k_deg(const int* __restrict__ dst, int* __restrict__ deg, int n) {
    int e = blockIdx.x * blockDim.x + threadIdx.x;
    if (e < n) atomicAdd(&deg[dst[e]], 1);
}

// wave-scan offsets + norm: row_ptr[i] = disjoint region start (order arbitrary)
__global__ void k_off(const int* __restrict__ deg, int* __restrict__ row_ptr,
                      int* __restrict__ cursor, float* __restrict__ norm,
                      int* __restrict__ gcount, int n) {
    int i = blockIdx.x * blockDim.x + threadIdx.x;
    int lane = threadIdx.x & 63;
    int v = (i < n) ? deg[i] : 0;
    int s = v;
#pragma unroll
    for (int off = 1; off < 64; off <<= 1) {
        int t = __shfl_up(s, off);
        if (lane >= off) s += t;
    }
    int total = __shfl(s, 63);
    int base = 0;
    if (lane == 63) base = atomicAdd(gcount, total);
    base = __shfl(base, 63);
    int ex = base + s - v;
    if (i < n) {
        row_ptr[i] = ex;
        cursor[i]  = ex;
        norm[i] = 1.0f / sqrtf(fmaxf((float)v, 1.0f));
    }
}

__global__ void k_scatter(const int* __restrict__ src, const int* __restrict__ dst,
                          int* __restrict__ cursor, int* __restrict__ csr_src, int n) {
    int e = blockIdx.x * blockDim.x + threadIdx.x;
    if (e < n) {
        int d = dst[e];
        int pos = atomicAdd(&cursor[d], 1);
        csr_src[pos] = src[e];
    }
}

// ---------------- layer 0 fused: wave per node; reduce neighbors, then lane=j computes h0 ----
// h0 = relu((agg @ W0 + b0*sn) * norm); hn = h0 * norm

__global__ __launch_bounds__(256) void k_l0(const float2* __restrict__ nf,
                                            const float* __restrict__ norm,
                                            const int* __restrict__ row_ptr,
                                            const int* __restrict__ deg,
                                            const int* __restrict__ csr_src,
                                            const float* __restrict__ W0,
                                            const float* __restrict__ b0,
                                            float* __restrict__ h,
                                            float* __restrict__ hn,
                                            float* __restrict__ snorm, int n_nodes) {
    int lane = threadIdx.x & 63, wid = threadIdx.x >> 6;
    int n = blockIdx.x * 4 + wid;
    if (n >= n_nodes) return;
    int r0 = row_ptr[n], dc = deg[n];
    float a0 = 0.f, a1 = 0.f, sn = 0.f;
    for (int i = lane; i < dc; i += 64) {
        int s = csr_src[r0 + i];
        float ns = norm[s];
        float2 v = nf[s];
        a0 += v.x * ns;
        a1 += v.y * ns;
        sn += ns;
    }
#pragma unroll
    for (int off = 32; off; off >>= 1) {
        a0 += __shfl_xor(a0, off);
        a1 += __shfl_xor(a1, off);
        sn += __shfl_xor(sn, off);
    }
    float nn = norm[n];
    float v = (a0 * W0[lane] + a1 * W0[64 + lane] + b0[lane] * sn) * nn;
    v = fmaxf(v, 0.f);
    h[(size_t)n * 64 + lane] = v;
    hn[(size_t)n * 64 + lane] = v * nn;
    if (lane == 0) snorm[n] = sn;
}

// ---------------- aggregation: g[n] = sum_{s in N(n)} hn[s]  (hn pre-scaled) ----------------

__global__ __launch_bounds__(256) void k_agg(const float* __restrict__ hn,
                                             const int* __restrict__ row_ptr,
                                             const int* __restrict__ deg,
                                             const int* __restrict__ csr_src,
                                             float* __restrict__ g, int n_nodes) {
    int lane = threadIdx.x & 63, wid = threadIdx.x >> 6;
    int n = blockIdx.x * 4 + wid;
    if (n >= n_nodes) return;
    int r0 = row_ptr[n], dc = deg[n];
    float acc = 0.f;
    int i = 0;
    for (; i + 4 <= dc; i += 4) {
        int s0 = csr_src[r0 + i + 0];
        int s1 = csr_src[r0 + i + 1];
        int s2 = csr_src[r0 + i + 2];
        int s3 = csr_src[r0 + i + 3];
        float v0 = hn[(size_t)s0 * 64 + lane];
        float v1 = hn[(size_t)s1 * 64 + lane];
        float v2 = hn[(size_t)s2 * 64 + lane];
        float v3 = hn[(size_t)s3 * 64 + lane];
        acc += (v0 + v1) + (v2 + v3);
    }
    for (; i < dc; ++i) acc += hn[(size_t)csr_src[r0 + i] * 64 + lane];
    g[(size_t)n * 64 + lane] = acc;
}

// ---------------- dense: h_out = relu((g@W + b*snorm)*norm) + h_in; hn_out optional ----------------

__global__ __launch_bounds__(256) void k_mv(const float* __restrict__ g,
                                            const float* __restrict__ h_in,
                                            const float* __restrict__ W,
                                            const float* __restrict__ b,
                                            const float* __restrict__ norm,
                                            const float* __restrict__ snorm,
                                            float* __restrict__ h_out,
                                            float* __restrict__ hn_out, int n_nodes) {
    int lane = threadIdx.x & 63, wid = threadIdx.x >> 6;
    int n = blockIdx.x * 64 + lane;
    if (n >= n_nodes) return;
    const int j0 = wid * 16;
    float sn = snorm[n];
    float y[16];
    const float* bj = b + j0;
#pragma unroll
    for (int q = 0; q < 16; ++q) y[q] = bj[q] * sn;
    const float4* g4 = (const float4*)(g + (size_t)n * 64);
    const float* Wj = W + j0;
#pragma unroll
    for (int k4 = 0; k4 < 16; ++k4) {
        float4 xv = g4[k4];
        const float* w0 = Wj + (k4 * 4 + 0) * 64;
        const float* w1 = Wj + (k4 * 4 + 1) * 64;
        const float* w2 = Wj + (k4 * 4 + 2) * 64;
        const float* w3 = Wj + (k4 * 4 + 3) * 64;
#pragma unroll
        for (int q = 0; q < 16; ++q) {
            y[q] = fmaf(xv.x, w0[q], y[q]);
            y[q] = fmaf(xv.y, w1[q], y[q]);
            y[q] = fmaf(xv.z, w2[q], y[q]);
            y[q] = fmaf(xv.w, w3[q], y[q]);
        }
    }
    float nn = norm[n];
    const float4* h4 = (const float4*)(h_in + (size_t)n * 64 + j0);
    float4* o4 = (float4*)(h_out + (size_t)n * 64 + j0);
#pragma unroll
    for (int q4 = 0; q4 < 4; ++q4) {
        float4 hv = h4[q4];
        float4 ov;
        ov.x = fmaxf(y[q4*4+0] * nn, 0.f) + hv.x;
        ov.y = fmaxf(y[q4*4+1] * nn, 0.f) + hv.y;
        ov.z = fmaxf(y[q4*4+2] * nn, 0.f) + hv.z;
        ov.w = fmaxf(y[q4*4+3] * nn, 0.f) + hv.w;
        o4[q4] = ov;
    }
    if (hn_out) {
        float4* s4 = (float4*)(hn_out + (size_t)n * 64 + j0);
#pragma unroll
        for (int q4 = 0; q4 < 4; ++q4) {
            float4 ov = o4[q4];
            float4 sv;
            sv.x = ov.x * nn; sv.y = ov.y * nn; sv.z = ov.z * nn; sv.w = ov.w * nn;
            s4[q4] = sv;
        }
    }
}

// ---------------- A/B projection: block 512 = 8 waves ----------------

__global__ __launch_bounds__(512) void k_mv2(const float* __restrict__ h,
                                             const float* __restrict__ M0,
                                             unsigned short* __restrict__ Ab,
                                             unsigned short* __restrict__ Bb,
                                             int n_nodes) {
    int lane = threadIdx.x & 63, wid = threadIdx.x >> 6;
    int n = blockIdx.x * 64 + lane;
    if (n >= n_nodes) return;
    const int tbl = wid >> 2;
    const int j0 = (wid & 3) * 16;
    float y[16];
#pragma unroll
    for (int q = 0; q < 16; ++q) y[q] = 0.f;
    const float4* h4 = (const float4*)(h + (size_t)n * 64);
    const float* Wj = M0 + tbl * 4096 + j0;
#pragma unroll
    for (int k4 = 0; k4 < 16; ++k4) {
        float4 xv = h4[k4];
        const float* w0 = Wj + (k4 * 4 + 0) * 64;
        const float* w1 = Wj + (k4 * 4 + 1) * 64;
        const float* w2 = Wj + (k4 * 4 + 2) * 64;
        const float* w3 = Wj + (k4 * 4 + 3) * 64;
#pragma unroll
        for (int q = 0; q < 16; ++q) {
            y[q] = fmaf(xv.x, w0[q], y[q]);
            y[q] = fmaf(xv.y, w1[q], y[q]);
            y[q] = fmaf(xv.z, w2[q], y[q]);
            y[q] = fmaf(xv.w, w3[q], y[q]);
        }
    }
    unsigned short* Ot = (tbl ? Bb : Ab) + (size_t)n * 64 + j0;
    uint4* o4 = (uint4*)Ot;
#pragma unroll
    for (int q = 0; q < 2; ++q) {
        uint4 ov;
        ov.x = (unsigned int)f2bf(y[q*8+0]) | ((unsigned int)f2bf(y[q*8+1]) << 16);
        ov.y = (unsigned int)f2bf(y[q*8+2]) | ((unsigned int)f2bf(y[q*8+3]) << 16);
        ov.z = (unsigned int)f2bf(y[q*8+4]) | ((unsigned int)f2bf(y[q*8+5]) << 16);
        ov.w = (unsigned int)f2bf(y[q*8+6]) | ((unsigned int)f2bf(y[q*8+7]) << 16);
        o4[q] = ov;
    }
}

// ---------------- tiny embedding projections + combo table ----------------

__global__ void k_small(const float* __restrict__ curr_emb, const float* __restrict__ pay_emb,
                        const float* __restrict__ M0, float* __restrict__ C1,
                        float* __restrict__ C2, float* __restrict__ P) {
    int tid = threadIdx.x;
    for (int idx = tid; idx < 15 * 64; idx += blockDim.x) {
        int c = idx >> 6, j = idx & 63;
        float s1 = 0.f, s2 = 0.f;
        for (int k = 0; k < 8; ++k) {
            float ce = curr_emb[c * 8 + k];
            s1 += ce * M0[(128 + k) * 64 + j];
            s2 += ce * M0[(136 + k) * 64 + j];
        }
        C1[idx] = s1;
        C2[idx] = s2;
    }
    for (int idx = tid; idx < 7 * 64; idx += blockDim.x) {
        int p = idx >> 6, j = idx & 63;
        float s = 0.f;
        for (int k = 0; k < 4; ++k) s += pay_emb[p * 4 + k] * M0[(144 + k) * 64 + j];
        P[idx] = s;
    }
}

// T[(c1*15+c2)*7+p][j] = C1[c1][j] + C2[c2][j] + P[p][j] + bM0[j]
__global__ void k_combo(const float* __restrict__ C1, const float* __restrict__ C2,
                        const float* __restrict__ P, const float* __restrict__ bM0,
                        float* __restrict__ T, int total) {
    int idx = blockIdx.x * blockDim.x + threadIdx.x;
    if (idx < total) {
        int j = idx & 63, c = idx >> 6;
        int p = c % 7, cc = c / 7;
        int c2 = cc % 15, c1 = cc / 15;
        T[idx] = C1[c1 * 64 + j] + C2[c2 * 64 + j] + P[p * 64 + j] + bM0[j];
    }
}

// ---------------- edge MLP — thread-per-edge (round-4 proven version) ----------------

__global__ __launch_bounds__(256, 2) void k_edge(const unsigned short* __restrict__ Ab,
                                                 const unsigned short* __restrict__ Bb,
                                                 const float* __restrict__ T,
                                                 const float* __restrict__ M0,
                                                 const float* __restrict__ M1,
                                                 const float* __restrict__ bM1,
                                                 const float* __restrict__ M2,
                                                 const float* __restrict__ bM2,
                                                 const int* __restrict__ src,
                                                 const int* __restrict__ dst,
                                                 const int* __restrict__ pc,
                                                 const int* __restrict__ rc,
                                                 const int* __restrict__ pf,
                                                 const float* __restrict__ num,
                                                 float* __restrict__ out, int n_edges) {
    int e = blockIdx.x * blockDim.x + threadIdx.x;
    if (e >= n_edges) return;
    int s = src[e], d = dst[e];
    int combo = (pc[e] * 15 + rc[e]) * 7 + pf[e];
    float nk[5];
#pragma unroll
    for (int k = 0; k < 5; ++k) nk[k] = num[(size_t)e * 5 + k];

    float x0[64];
    const float4* t4 = (const float4*)(T + (size_t)combo * 64);
#pragma unroll
    for (int q = 0; q < 16; ++q) {
        float4 v = t4[q];
        x0[q*4+0] = v.x; x0[q*4+1] = v.y; x0[q*4+2] = v.z; x0[q*4+3] = v.w;
    }
    add_bf16_row(x0, Ab + (size_t)s * 64);
    add_bf16_row(x0, Bb + (size_t)d * 64);
#pragma unroll
    for (int k = 0; k < 5; ++k) {
        const float* m4 = M0 + (148 + k) * 64;
        float nkk = nk[k];
#pragma unroll
        for (int q = 0; q < 64; ++q) x0[q] = fmaf(nkk, m4[q], x0[q]);
    }
#pragma unroll
    for (int k = 0; k < 64; ++k) x0[k] = fmaxf(x0[k], 0.f);

    float lg0 = bM2[0], lg1 = bM2[1];
#pragma unroll
    for (int jh = 0; jh < 2; ++jh) {
        float x1[32];
        const float* bb = bM1 + jh * 32;
#pragma unroll
        for (int q = 0; q < 32; ++q) x1[q] = bb[q];
#pragma unroll
        for (int k = 0; k < 64; ++k) {
            float xk = x0[k];
            const float* mr = M1 + k * 64 + jh * 32;
#pragma unroll
            for (int q = 0; q < 32; ++q) x1[q] = fmaf(xk, mr[q], x1[q]);
        }
#pragma unroll
        for (int j = 0; j < 32; ++j) {
            float xv = fmaxf(x1[j], 0.f);
            int jj = jh * 32 + j;
            lg0 = fmaf(xv, M2[jj * 2 + 0], lg0);
            lg1 = fmaf(xv, M2[jj * 2 + 1], lg1);
        }
    }
    ((float2*)out)[e] = make_float2(lg0, lg1);
}

// ---------------- launch ----------------

extern "C" void kernel_launch(void* const* d_in, const int* in_sizes, int n_in,
                              void* d_out, int out_size, void* d_ws, size_t ws_size,
                              hipStream_t stream) {
    const float2* node_feats = (const float2*)d_in[0];
    const int*   src  = (const int*)d_in[1];
    const int*   dst  = (const int*)d_in[2];
    const int*   pc   = (const int*)d_in[3];
    const int*   rc   = (const int*)d_in[4];
    const int*   pf   = (const int*)d_in[5];
    const float* num  = (const float*)d_in[6];
    const float* W0   = (const float*)d_in[7];
    const float* b0   = (const float*)d_in[8];
    const float* W1   = (const float*)d_in[9];
    const float* b1   = (const float*)d_in[10];
    const float* W2   = (const float*)d_in[11];
    const float* b2   = (const float*)d_in[12];
    const float* curr_emb = (const float*)d_in[13];
    const float* pay_emb  = (const float*)d_in[14];
    const float* M0   = (const float*)d_in[15];
    const float* bM0  = (const float*)d_in[16];
    const float* M1   = (const float*)d_in[17];
    const float* bM1  = (const float*)d_in[18];
    const float* M2   = (const float*)d_in[19];
    const float* bM2  = (const float*)d_in[20];
    float* out = (float*)d_out;

    char* w = (char*)d_ws;
    auto alloc = [&](size_t bytes) {
        char* p = w;
        w += (bytes + 255) & ~size_t(255);
        return p;
    };
    int*    deg     = (int*)alloc(N_NODES * 4);
    int*    gcount  = (int*)alloc(256);
    float*  norm    = (float*)alloc(N_NODES * 4);
    float*  snorm   = (float*)alloc(N_NODES * 4);
    int*    row_ptr = (int*)alloc((N_NODES + 1) * 4);
    int*    cursor  = (int*)alloc(N_NODES * 4);
    int*    csr_src = (int*)alloc(N_EDGES * 4);
    float*  B1      = (float*)alloc(N_NODES * HID * 4);   // h0 -> h2
    float*  B2      = (float*)alloc(N_NODES * HID * 4);   // h0n -> h1n
    float*  B3      = (float*)alloc(N_NODES * HID * 4);   // g
    float*  B4      = (float*)alloc(N_NODES * HID * 4);   // h1
    unsigned short* Ab = (unsigned short*)alloc(N_NODES * HID * 2);
    unsigned short* Bb = (unsigned short*)alloc(N_NODES * HID * 2);
    float*  C1      = (float*)alloc(15 * 64 * 4);
    float*  C2      = (float*)alloc(15 * 64 * 4);
    float*  P       = (float*)alloc(7 * 64 * 4);
    float*  T       = (float*)alloc(15 * 15 * 7 * 64 * 4);

    hipMemsetAsync(deg, 0, N_NODES * 4, stream);
    hipMemsetAsync(gcount, 0, 256, stream);
    k_deg<<<(N_EDGES + 255) / 256, 256, 0, stream>>>(dst, deg, N_EDGES);
    k_off<<<(N_NODES + 255) / 256, 256, 0, stream>>>(deg, row_ptr, cursor, norm, gcount, N_NODES);
    k_scatter<<<(N_EDGES + 255) / 256, 256, 0, stream>>>(src, dst, cursor, csr_src, N_EDGES);
    // layer 0 (fused agg + dense, wave per node)
    k_l0<<<(N_NODES + 3) / 4, 256, 0, stream>>>(node_feats, norm, row_ptr, deg, csr_src,
                                                W0, b0, B1, B2, snorm, N_NODES);
    // layer 1
    k_agg<<<(N_NODES + 3) / 4, 256, 0, stream>>>(B2, row_ptr, deg, csr_src, B3, N_NODES);
    k_mv<<<(N_NODES + 63) / 64, 256, 0, stream>>>(B3, B1, W1, b1, norm, snorm, B4, B2, N_NODES);
    // layer 2
    k_agg<<<(N_NODES + 3) / 4, 256, 0, stream>>>(B2, row_ptr, deg, csr_src, B3, N_NODES);
    k_mv<<<(N_NODES + 63) / 64, 256, 0, stream>>>(B3, B4, W2, b2, norm, snorm, B1, nullptr, N_NODES);
    // edge path
    k_small<<<1, 256, 0, stream>>>(curr_emb, pay_emb, M0, C1, C2, P);
    k_combo<<<(15 * 15 * 7 * 64 + 255) / 256, 256, 0, stream>>>(C1, C2, P, bM0, T, 15 * 15 * 7 * 64);
    k_mv2<<<(N_NODES + 63) / 64, 512, 0, stream>>>(B1, M0, Ab, Bb, N_NODES);
    k_edge<<<(N_EDGES + 255) / 256, 256, 0, stream>>>(Ab, Bb, T, M0, M1, bM1, M2, bM2,
                                                      src, dst, pc, rc, pf, num, out, N_EDGES);
}

// Round 9
// 602.265 us; speedup vs baseline: 1.0328x; 1.0328x over previous
//
#include <hip/hip_runtime.h>
#include <hip/hip_bf16.h>

#define N_NODES 50000
#define N_EDGES 800000
#define HID 64

typedef __attribute__((ext_vector_type(2))) float f32x2;

__device__ __forceinline__ unsigned short f2bf(float f) {
    union { float f; unsigned int i; } v;
    v.f = f;
    unsigned int b = v.i;
    return (unsigned short)((b + 0x7FFFu + ((b >> 16) & 1u)) >> 16);
}

__device__ __forceinline__ float bf2f(unsigned short u) {
    union { unsigned int i; float f; } t;
    t.i = ((unsigned int)u) << 16;
    return t.f;
}

// two bf16 packed in a uint -> f32x2
__device__ __forceinline__ f32x2 bfpair(unsigned int u) {
    union { unsigned int i; float f; } lo, hi;
    lo.i = u << 16;
    hi.i = u & 0xFFFF0000u;
    f32x2 r;
    r[0] = lo.f;
    r[1] = hi.f;
    return r;
}

// ---------------- CSR build ----------------

__global__ void k_deg(const int* __restrict__ dst, int* __restrict__ deg, int n) {
    int e = blockIdx.x * blockDim.x + threadIdx.x;
    if (e < n) atomicAdd(&deg[dst[e]], 1);
}

// wave-scan offsets + norm: row_ptr[i] = disjoint region start (order arbitrary)
__global__ void k_off(const int* __restrict__ deg, int* __restrict__ row_ptr,
                      int* __restrict__ cursor, float* __restrict__ norm,
                      int* __restrict__ gcount, int n) {
    int i = blockIdx.x * blockDim.x + threadIdx.x;
    int lane = threadIdx.x & 63;
    int v = (i < n) ? deg[i] : 0;
    int s = v;
#pragma unroll
    for (int off = 1; off < 64; off <<= 1) {
        int t = __shfl_up(s, off);
        if (lane >= off) s += t;
    }
    int total = __shfl(s, 63);
    int base = 0;
    if (lane == 63) base = atomicAdd(gcount, total);
    base = __shfl(base, 63);
    int ex = base + s - v;
    if (i < n) {
        row_ptr[i] = ex;
        cursor[i]  = ex;
        norm[i] = 1.0f / sqrtf(fmaxf((float)v, 1.0f));
    }
}

__global__ void k_scatter(const int* __restrict__ src, const int* __restrict__ dst,
                          int* __restrict__ cursor, int* __restrict__ csr_src, int n) {
    int e = blockIdx.x * blockDim.x + threadIdx.x;
    if (e < n) {
        int d = dst[e];
        int pos = atomicAdd(&cursor[d], 1);
        csr_src[pos] = src[e];
    }
}

// ---------------- layer 0 fused: wave per node; reduce neighbors, then lane=j computes h0 ----
// h0 = relu((agg @ W0 + b0*sn) * norm); hn = bf16(h0 * norm)

__global__ __launch_bounds__(256) void k_l0(const float2* __restrict__ nf,
                                            const float* __restrict__ norm,
                                            const int* __restrict__ row_ptr,
                                            const int* __restrict__ deg,
                                            const int* __restrict__ csr_src,
                                            const float* __restrict__ W0,
                                            const float* __restrict__ b0,
                                            float* __restrict__ h,
                                            unsigned short* __restrict__ hn,
                                            float* __restrict__ snorm, int n_nodes) {
    int lane = threadIdx.x & 63, wid = threadIdx.x >> 6;
    int n = blockIdx.x * 4 + wid;
    if (n >= n_nodes) return;
    int r0 = row_ptr[n], dc = deg[n];
    float a0 = 0.f, a1 = 0.f, sn = 0.f;
    for (int i = lane; i < dc; i += 64) {
        int s = csr_src[r0 + i];
        float ns = norm[s];
        float2 v = nf[s];
        a0 += v.x * ns;
        a1 += v.y * ns;
        sn += ns;
    }
#pragma unroll
    for (int off = 32; off; off >>= 1) {
        a0 += __shfl_xor(a0, off);
        a1 += __shfl_xor(a1, off);
        sn += __shfl_xor(sn, off);
    }
    float nn = norm[n];
    float v = (a0 * W0[lane] + a1 * W0[64 + lane] + b0[lane] * sn) * nn;
    v = fmaxf(v, 0.f);
    h[(size_t)n * 64 + lane] = v;
    hn[(size_t)n * 64 + lane] = f2bf(v * nn);
    if (lane == 0) snorm[n] = sn;
}

// ---------------- aggregation: g[n] = sum_{s in N(n)} hn[s]  (hn pre-scaled, bf16) ----------------

__global__ __launch_bounds__(256) void k_agg(const unsigned short* __restrict__ hn,
                                             const int* __restrict__ row_ptr,
                                             const int* __restrict__ deg,
                                             const int* __restrict__ csr_src,
                                             float* __restrict__ g, int n_nodes) {
    int lane = threadIdx.x & 63, wid = threadIdx.x >> 6;
    int n = blockIdx.x * 4 + wid;
    if (n >= n_nodes) return;
    int r0 = row_ptr[n], dc = deg[n];
    float acc = 0.f;
    int i = 0;
    for (; i + 4 <= dc; i += 4) {
        int s0 = csr_src[r0 + i + 0];
        int s1 = csr_src[r0 + i + 1];
        int s2 = csr_src[r0 + i + 2];
        int s3 = csr_src[r0 + i + 3];
        float v0 = bf2f(hn[(size_t)s0 * 64 + lane]);
        float v1 = bf2f(hn[(size_t)s1 * 64 + lane]);
        float v2 = bf2f(hn[(size_t)s2 * 64 + lane]);
        float v3 = bf2f(hn[(size_t)s3 * 64 + lane]);
        acc += (v0 + v1) + (v2 + v3);
    }
    for (; i < dc; ++i) acc += bf2f(hn[(size_t)csr_src[r0 + i] * 64 + lane]);
    g[(size_t)n * 64 + lane] = acc;
}

// ---------------- dense: h_out = relu((g@W + b*snorm)*norm) + h_in; hn_out (bf16) optional ----

__global__ __launch_bounds__(256) void k_mv(const float* __restrict__ g,
                                            const float* __restrict__ h_in,
                                            const float* __restrict__ W,
                                            const float* __restrict__ b,
                                            const float* __restrict__ norm,
                                            const float* __restrict__ snorm,
                                            float* __restrict__ h_out,
                                            unsigned short* __restrict__ hn_out, int n_nodes) {
    int lane = threadIdx.x & 63, wid = threadIdx.x >> 6;
    int n = blockIdx.x * 64 + lane;
    if (n >= n_nodes) return;
    const int j0 = wid * 16;
    float sn = snorm[n];
    float y[16];
    const float* bj = b + j0;
#pragma unroll
    for (int q = 0; q < 16; ++q) y[q] = bj[q] * sn;
    const float4* g4 = (const float4*)(g + (size_t)n * 64);
    const float* Wj = W + j0;
#pragma unroll
    for (int k4 = 0; k4 < 16; ++k4) {
        float4 xv = g4[k4];
        const float* w0 = Wj + (k4 * 4 + 0) * 64;
        const float* w1 = Wj + (k4 * 4 + 1) * 64;
        const float* w2 = Wj + (k4 * 4 + 2) * 64;
        const float* w3 = Wj + (k4 * 4 + 3) * 64;
#pragma unroll
        for (int q = 0; q < 16; ++q) {
            y[q] = fmaf(xv.x, w0[q], y[q]);
            y[q] = fmaf(xv.y, w1[q], y[q]);
            y[q] = fmaf(xv.z, w2[q], y[q]);
            y[q] = fmaf(xv.w, w3[q], y[q]);
        }
    }
    float nn = norm[n];
    const float4* h4 = (const float4*)(h_in + (size_t)n * 64 + j0);
    float4* o4 = (float4*)(h_out + (size_t)n * 64 + j0);
    float ov[16];
#pragma unroll
    for (int q4 = 0; q4 < 4; ++q4) {
        float4 hv = h4[q4];
        float4 o;
        o.x = fmaxf(y[q4*4+0] * nn, 0.f) + hv.x;
        o.y = fmaxf(y[q4*4+1] * nn, 0.f) + hv.y;
        o.z = fmaxf(y[q4*4+2] * nn, 0.f) + hv.z;
        o.w = fmaxf(y[q4*4+3] * nn, 0.f) + hv.w;
        o4[q4] = o;
        ov[q4*4+0] = o.x; ov[q4*4+1] = o.y; ov[q4*4+2] = o.z; ov[q4*4+3] = o.w;
    }
    if (hn_out) {
        uint4* s4 = (uint4*)(hn_out + (size_t)n * 64 + j0);
#pragma unroll
        for (int q8 = 0; q8 < 2; ++q8) {
            uint4 w;
            w.x = (unsigned int)f2bf(ov[q8*8+0] * nn) | ((unsigned int)f2bf(ov[q8*8+1] * nn) << 16);
            w.y = (unsigned int)f2bf(ov[q8*8+2] * nn) | ((unsigned int)f2bf(ov[q8*8+3] * nn) << 16);
            w.z = (unsigned int)f2bf(ov[q8*8+4] * nn) | ((unsigned int)f2bf(ov[q8*8+5] * nn) << 16);
            w.w = (unsigned int)f2bf(ov[q8*8+6] * nn) | ((unsigned int)f2bf(ov[q8*8+7] * nn) << 16);
            s4[q8] = w;
        }
    }
}

// ---------------- A/B projection: block 512 = 8 waves ----------------

__global__ __launch_bounds__(512) void k_mv2(const float* __restrict__ h,
                                             const float* __restrict__ M0,
                                             unsigned short* __restrict__ Ab,
                                             unsigned short* __restrict__ Bb,
                                             int n_nodes) {
    int lane = threadIdx.x & 63, wid = threadIdx.x >> 6;
    int n = blockIdx.x * 64 + lane;
    if (n >= n_nodes) return;
    const int tbl = wid >> 2;
    const int j0 = (wid & 3) * 16;
    float y[16];
#pragma unroll
    for (int q = 0; q < 16; ++q) y[q] = 0.f;
    const float4* h4 = (const float4*)(h + (size_t)n * 64);
    const float* Wj = M0 + tbl * 4096 + j0;
#pragma unroll
    for (int k4 = 0; k4 < 16; ++k4) {
        float4 xv = h4[k4];
        const float* w0 = Wj + (k4 * 4 + 0) * 64;
        const float* w1 = Wj + (k4 * 4 + 1) * 64;
        const float* w2 = Wj + (k4 * 4 + 2) * 64;
        const float* w3 = Wj + (k4 * 4 + 3) * 64;
#pragma unroll
        for (int q = 0; q < 16; ++q) {
            y[q] = fmaf(xv.x, w0[q], y[q]);
            y[q] = fmaf(xv.y, w1[q], y[q]);
            y[q] = fmaf(xv.z, w2[q], y[q]);
            y[q] = fmaf(xv.w, w3[q], y[q]);
        }
    }
    unsigned short* Ot = (tbl ? Bb : Ab) + (size_t)n * 64 + j0;
    uint4* o4 = (uint4*)Ot;
#pragma unroll
    for (int q = 0; q < 2; ++q) {
        uint4 ov;
        ov.x = (unsigned int)f2bf(y[q*8+0]) | ((unsigned int)f2bf(y[q*8+1]) << 16);
        ov.y = (unsigned int)f2bf(y[q*8+2]) | ((unsigned int)f2bf(y[q*8+3]) << 16);
        ov.z = (unsigned int)f2bf(y[q*8+4]) | ((unsigned int)f2bf(y[q*8+5]) << 16);
        ov.w = (unsigned int)f2bf(y[q*8+6]) | ((unsigned int)f2bf(y[q*8+7]) << 16);
        o4[q] = ov;
    }
}

// ---------------- tiny embedding projections + combo table ----------------

__global__ void k_small(const float* __restrict__ curr_emb, const float* __restrict__ pay_emb,
                        const float* __restrict__ M0, float* __restrict__ C1,
                        float* __restrict__ C2, float* __restrict__ P) {
    int tid = threadIdx.x;
    for (int idx = tid; idx < 15 * 64; idx += blockDim.x) {
        int c = idx >> 6, j = idx & 63;
        float s1 = 0.f, s2 = 0.f;
        for (int k = 0; k < 8; ++k) {
            float ce = curr_emb[c * 8 + k];
            s1 += ce * M0[(128 + k) * 64 + j];
            s2 += ce * M0[(136 + k) * 64 + j];
        }
        C1[idx] = s1;
        C2[idx] = s2;
    }
    for (int idx = tid; idx < 7 * 64; idx += blockDim.x) {
        int p = idx >> 6, j = idx & 63;
        float s = 0.f;
        for (int k = 0; k < 4; ++k) s += pay_emb[p * 4 + k] * M0[(144 + k) * 64 + j];
        P[idx] = s;
    }
}

// T[(c1*15+c2)*7+p][j] = C1[c1][j] + C2[c2][j] + P[p][j] + bM0[j]
__global__ void k_combo(const float* __restrict__ C1, const float* __restrict__ C2,
                        const float* __restrict__ P, const float* __restrict__ bM0,
                        float* __restrict__ T, int total) {
    int idx = blockIdx.x * blockDim.x + threadIdx.x;
    if (idx < total) {
        int j = idx & 63, c = idx >> 6;
        int p = c % 7, cc = c / 7;
        int c2 = cc % 15, c1 = cc / 15;
        T[idx] = C1[c1 * 64 + j] + C2[c2 * 64 + j] + P[p * 64 + j] + bM0[j];
    }
}

// ---------------- edge MLP — thread-per-edge, packed-f32 math ----------------

__global__ __launch_bounds__(256, 2) void k_edge(const unsigned short* __restrict__ Ab,
                                                 const unsigned short* __restrict__ Bb,
                                                 const float* __restrict__ T,
                                                 const float* __restrict__ M0,
                                                 const float* __restrict__ M1,
                                                 const float* __restrict__ bM1,
                                                 const float* __restrict__ M2,
                                                 const float* __restrict__ bM2,
                                                 const int* __restrict__ src,
                                                 const int* __restrict__ dst,
                                                 const int* __restrict__ pc,
                                                 const int* __restrict__ rc,
                                                 const int* __restrict__ pf,
                                                 const float* __restrict__ num,
                                                 float* __restrict__ out, int n_edges) {
    int e = blockIdx.x * blockDim.x + threadIdx.x;
    if (e >= n_edges) return;
    int s = src[e], d = dst[e];
    int combo = (pc[e] * 15 + rc[e]) * 7 + pf[e];
    float nk[5];
#pragma unroll
    for (int k = 0; k < 5; ++k) nk[k] = num[(size_t)e * 5 + k];

    // x0 as 32 packed float2 lanes (v_pk_* ops)
    f32x2 x0[32];
    const f32x2* t2 = (const f32x2*)(T + (size_t)combo * 64);
#pragma unroll
    for (int q = 0; q < 32; ++q) x0[q] = t2[q];

    const uint4* ra = (const uint4*)(Ab + (size_t)s * 64);
#pragma unroll
    for (int q = 0; q < 8; ++q) {
        uint4 v = ra[q];
        x0[q*4+0] += bfpair(v.x);
        x0[q*4+1] += bfpair(v.y);
        x0[q*4+2] += bfpair(v.z);
        x0[q*4+3] += bfpair(v.w);
    }
    const uint4* rb = (const uint4*)(Bb + (size_t)d * 64);
#pragma unroll
    for (int q = 0; q < 8; ++q) {
        uint4 v = rb[q];
        x0[q*4+0] += bfpair(v.x);
        x0[q*4+1] += bfpair(v.y);
        x0[q*4+2] += bfpair(v.z);
        x0[q*4+3] += bfpair(v.w);
    }
#pragma unroll
    for (int k = 0; k < 5; ++k) {
        const f32x2* mp = (const f32x2*)(M0 + (148 + k) * 64);
        f32x2 nv;
        nv[0] = nk[k]; nv[1] = nk[k];
#pragma unroll
        for (int q = 0; q < 32; ++q) x0[q] = __builtin_elementwise_fma(nv, mp[q], x0[q]);
    }
    f32x2 zero2;
    zero2[0] = 0.f; zero2[1] = 0.f;
#pragma unroll
    for (int q = 0; q < 32; ++q) x0[q] = __builtin_elementwise_max(x0[q], zero2);

    float lg0 = bM2[0], lg1 = bM2[1];
#pragma unroll
    for (int jh = 0; jh < 2; ++jh) {
        f32x2 x1[16];
        const f32x2* bb = (const f32x2*)(bM1 + jh * 32);
#pragma unroll
        for (int q = 0; q < 16; ++q) x1[q] = bb[q];
#pragma unroll
        for (int k = 0; k < 64; ++k) {
            float xk = x0[k >> 1][k & 1];
            f32x2 xv;
            xv[0] = xk; xv[1] = xk;
            const f32x2* mr = (const f32x2*)(M1 + k * 64 + jh * 32);
#pragma unroll
            for (int q = 0; q < 16; ++q) x1[q] = __builtin_elementwise_fma(xv, mr[q], x1[q]);
        }
#pragma unroll
        for (int q = 0; q < 16; ++q) {
            f32x2 xv = __builtin_elementwise_max(x1[q], zero2);
            int j = jh * 32 + q * 2;
            lg0 = fmaf(xv[0], M2[j * 2 + 0], lg0);
            lg1 = fmaf(xv[0], M2[j * 2 + 1], lg1);
            lg0 = fmaf(xv[1], M2[j * 2 + 2], lg0);
            lg1 = fmaf(xv[1], M2[j * 2 + 3], lg1);
        }
    }
    ((float2*)out)[e] = make_float2(lg0, lg1);
}

// ---------------- launch ----------------

extern "C" void kernel_launch(void* const* d_in, const int* in_sizes, int n_in,
                              void* d_out, int out_size, void* d_ws, size_t ws_size,
                              hipStream_t stream) {
    const float2* node_feats = (const float2*)d_in[0];
    const int*   src  = (const int*)d_in[1];
    const int*   dst  = (const int*)d_in[2];
    const int*   pc   = (const int*)d_in[3];
    const int*   rc   = (const int*)d_in[4];
    const int*   pf   = (const int*)d_in[5];
    const float* num  = (const float*)d_in[6];
    const float* W0   = (const float*)d_in[7];
    const float* b0   = (const float*)d_in[8];
    const float* W1   = (const float*)d_in[9];
    const float* b1   = (const float*)d_in[10];
    const float* W2   = (const float*)d_in[11];
    const float* b2   = (const float*)d_in[12];
    const float* curr_emb = (const float*)d_in[13];
    const float* pay_emb  = (const float*)d_in[14];
    const float* M0   = (const float*)d_in[15];
    const float* bM0  = (const float*)d_in[16];
    const float* M1   = (const float*)d_in[17];
    const float* bM1  = (const float*)d_in[18];
    const float* M2   = (const float*)d_in[19];
    const float* bM2  = (const float*)d_in[20];
    float* out = (float*)d_out;

    char* w = (char*)d_ws;
    auto alloc = [&](size_t bytes) {
        char* p = w;
        w += (bytes + 255) & ~size_t(255);
        return p;
    };
    int*    deg     = (int*)alloc(N_NODES * 4);
    int*    gcount  = (int*)alloc(256);
    float*  norm    = (float*)alloc(N_NODES * 4);
    float*  snorm   = (float*)alloc(N_NODES * 4);
    int*    row_ptr = (int*)alloc((N_NODES + 1) * 4);
    int*    cursor  = (int*)alloc(N_NODES * 4);
    int*    csr_src = (int*)alloc(N_EDGES * 4);
    float*  B1      = (float*)alloc(N_NODES * HID * 4);             // h0 -> h2
    unsigned short* B2 = (unsigned short*)alloc(N_NODES * HID * 2); // hn (bf16)
    float*  B3      = (float*)alloc(N_NODES * HID * 4);             // g
    float*  B4      = (float*)alloc(N_NODES * HID * 4);             // h1
    unsigned short* Ab = (unsigned short*)alloc(N_NODES * HID * 2);
    unsigned short* Bb = (unsigned short*)alloc(N_NODES * HID * 2);
    float*  C1      = (float*)alloc(15 * 64 * 4);
    float*  C2      = (float*)alloc(15 * 64 * 4);
    float*  P       = (float*)alloc(7 * 64 * 4);
    float*  T       = (float*)alloc(15 * 15 * 7 * 64 * 4);

    hipMemsetAsync(deg, 0, N_NODES * 4, stream);
    hipMemsetAsync(gcount, 0, 256, stream);
    k_deg<<<(N_EDGES + 255) / 256, 256, 0, stream>>>(dst, deg, N_EDGES);
    k_off<<<(N_NODES + 255) / 256, 256, 0, stream>>>(deg, row_ptr, cursor, norm, gcount, N_NODES);
    k_scatter<<<(N_EDGES + 255) / 256, 256, 0, stream>>>(src, dst, cursor, csr_src, N_EDGES);
    // layer 0 (fused agg + dense, wave per node)
    k_l0<<<(N_NODES + 3) / 4, 256, 0, stream>>>(node_feats, norm, row_ptr, deg, csr_src,
                                                W0, b0, B1, B2, snorm, N_NODES);
    // layer 1
    k_agg<<<(N_NODES + 3) / 4, 256, 0, stream>>>(B2, row_ptr, deg, csr_src, B3, N_NODES);
    k_mv<<<(N_NODES + 63) / 64, 256, 0, stream>>>(B3, B1, W1, b1, norm, snorm, B4, B2, N_NODES);
    // layer 2
    k_agg<<<(N_NODES + 3) / 4, 256, 0, stream>>>(B2, row_ptr, deg, csr_src, B3, N_NODES);
    k_mv<<<(N_NODES + 63) / 64, 256, 0, stream>>>(B3, B4, W2, b2, norm, snorm, B1, nullptr, N_NODES);
    // edge path
    k_small<<<1, 256, 0, stream>>>(curr_emb, pay_emb, M0, C1, C2, P);
    k_combo<<<(15 * 15 * 7 * 64 + 255) / 256, 256, 0, stream>>>(C1, C2, P, bM0, T, 15 * 15 * 7 * 64);
    k_mv2<<<(N_NODES + 63) / 64, 512, 0, stream>>>(B1, M0, Ab, Bb, N_NODES);
    k_edge<<<(N_EDGES + 255) / 256, 256, 0, stream>>>(Ab, Bb, T, M0, M1, bM1, M2, bM2,
                                                      src, dst, pc, rc, pf, num, out, N_EDGES);
}

// Round 10
// 570.629 us; speedup vs baseline: 1.0900x; 1.0554x over previous
//
#include <hip/hip_runtime.h>
#include <hip/hip_bf16.h>

#define N_NODES 50000
#define N_EDGES 800000
#define HID 64

typedef __attribute__((ext_vector_type(2))) float f32x2;

__device__ __forceinline__ unsigned short f2bf(float f) {
    union { float f; unsigned int i; } v;
    v.f = f;
    unsigned int b = v.i;
    return (unsigned short)((b + 0x7FFFu + ((b >> 16) & 1u)) >> 16);
}

__device__ __forceinline__ float bf2f(unsigned short u) {
    union { unsigned int i; float f; } t;
    t.i = ((unsigned int)u) << 16;
    return t.f;
}

// two bf16 packed in a uint -> f32x2
__device__ __forceinline__ f32x2 bfpair(unsigned int u) {
    union { unsigned int i; float f; } lo, hi;
    lo.i = u << 16;
    hi.i = u & 0xFFFF0000u;
    f32x2 r;
    r[0] = lo.f;
    r[1] = hi.f;
    return r;
}

__device__ __forceinline__ unsigned int pkbf(f32x2 v) {
    return (unsigned int)f2bf(v[0]) | ((unsigned int)f2bf(v[1]) << 16);
}

// ---------------- CSR build ----------------

__global__ void k_deg(const int* __restrict__ dst, int* __restrict__ deg, int n) {
    int e = blockIdx.x * blockDim.x + threadIdx.x;
    if (e < n) atomicAdd(&deg[dst[e]], 1);
}

// wave-scan offsets + norm: row_ptr[i] = disjoint region start (order arbitrary)
__global__ void k_off(const int* __restrict__ deg, int* __restrict__ row_ptr,
                      int* __restrict__ cursor, float* __restrict__ norm,
                      int* __restrict__ gcount, int n) {
    int i = blockIdx.x * blockDim.x + threadIdx.x;
    int lane = threadIdx.x & 63;
    int v = (i < n) ? deg[i] : 0;
    int s = v;
#pragma unroll
    for (int off = 1; off < 64; off <<= 1) {
        int t = __shfl_up(s, off);
        if (lane >= off) s += t;
    }
    int total = __shfl(s, 63);
    int base = 0;
    if (lane == 63) base = atomicAdd(gcount, total);
    base = __shfl(base, 63);
    int ex = base + s - v;
    if (i < n) {
        row_ptr[i] = ex;
        cursor[i]  = ex;
        norm[i] = 1.0f / sqrtf(fmaxf((float)v, 1.0f));
    }
}

__global__ void k_scatter(const int* __restrict__ src, const int* __restrict__ dst,
                          int* __restrict__ cursor, int* __restrict__ csr_src, int n) {
    int e = blockIdx.x * blockDim.x + threadIdx.x;
    if (e < n) {
        int d = dst[e];
        int pos = atomicAdd(&cursor[d], 1);
        csr_src[pos] = src[e];
    }
}

// ---------------- layer 0 fused: wave per node; reduce neighbors, then lane=j computes h0 ----
// h0 = relu((agg @ W0 + b0*sn) * norm); hn = bf16(h0 * norm)

__global__ __launch_bounds__(256) void k_l0(const float2* __restrict__ nf,
                                            const float* __restrict__ norm,
                                            const int* __restrict__ row_ptr,
                                            const int* __restrict__ deg,
                                            const int* __restrict__ csr_src,
                                            const float* __restrict__ W0,
                                            const float* __restrict__ b0,
                                            float* __restrict__ h,
                                            unsigned short* __restrict__ hn,
                                            float* __restrict__ snorm, int n_nodes) {
    int lane = threadIdx.x & 63, wid = threadIdx.x >> 6;
    int n = blockIdx.x * 4 + wid;
    if (n >= n_nodes) return;
    int r0 = row_ptr[n], dc = deg[n];
    float a0 = 0.f, a1 = 0.f, sn = 0.f;
    for (int i = lane; i < dc; i += 64) {
        int s = csr_src[r0 + i];
        float ns = norm[s];
        float2 v = nf[s];
        a0 += v.x * ns;
        a1 += v.y * ns;
        sn += ns;
    }
#pragma unroll
    for (int off = 32; off; off >>= 1) {
        a0 += __shfl_xor(a0, off);
        a1 += __shfl_xor(a1, off);
        sn += __shfl_xor(sn, off);
    }
    float nn = norm[n];
    float v = (a0 * W0[lane] + a1 * W0[64 + lane] + b0[lane] * sn) * nn;
    v = fmaxf(v, 0.f);
    h[(size_t)n * 64 + lane] = v;
    hn[(size_t)n * 64 + lane] = f2bf(v * nn);
    if (lane == 0) snorm[n] = sn;
}

// ---------------- aggregation: g[n] = sum_{s in N(n)} hn[s]  (bf16, half-wave per row) -----
// lanes 0-31 handle neighbor i, lanes 32-63 neighbor i+1; lane reads a uint (2 features).

__global__ __launch_bounds__(256) void k_agg(const unsigned short* __restrict__ hn,
                                             const int* __restrict__ row_ptr,
                                             const int* __restrict__ deg,
                                             const int* __restrict__ csr_src,
                                             float* __restrict__ g, int n_nodes) {
    int lane = threadIdx.x & 63, wid = threadIdx.x >> 6;
    int n = blockIdx.x * 4 + wid;
    if (n >= n_nodes) return;
    const unsigned int* hnu = (const unsigned int*)hn;
    int r0 = row_ptr[n], dc = deg[n];
    int half = lane >> 5;      // 0/1: which neighbor of the pair
    int fl = lane & 31;        // feature-pair index
    f32x2 acc;
    acc[0] = 0.f; acc[1] = 0.f;
    int i = 0;
    for (; i + 4 <= dc; i += 4) {
        int s0 = csr_src[r0 + i + half];
        int s1 = csr_src[r0 + i + 2 + half];
        acc += bfpair(hnu[(size_t)s0 * 32 + fl]);
        acc += bfpair(hnu[(size_t)s1 * 32 + fl]);
    }
    for (; i + 2 <= dc; i += 2) {
        int s0 = csr_src[r0 + i + half];
        acc += bfpair(hnu[(size_t)s0 * 32 + fl]);
    }
    if (i < dc && half == 0) {
        int s0 = csr_src[r0 + i];
        acc += bfpair(hnu[(size_t)s0 * 32 + fl]);
    }
    acc[0] += __shfl_xor(acc[0], 32);
    acc[1] += __shfl_xor(acc[1], 32);
    if (half == 0) ((float2*)g)[(size_t)n * 32 + fl] = make_float2(acc[0], acc[1]);
}

// ---------------- dense: h_out = relu((g@W + b*snorm)*norm) + h_in ----------------
// If Ab != null (layer 2): skip global h write; exchange h2 via LDS and emit
// bf16 tables Ab = h2 @ M0[0:64], Bb = h2 @ M0[64:128] instead.

__global__ __launch_bounds__(256) void k_mv(const float* __restrict__ g,
                                            const float* __restrict__ h_in,
                                            const float* __restrict__ W,
                                            const float* __restrict__ b,
                                            const float* __restrict__ norm,
                                            const float* __restrict__ snorm,
                                            float* __restrict__ h_out,
                                            unsigned short* __restrict__ hn_out,
                                            unsigned short* __restrict__ Ab,
                                            unsigned short* __restrict__ Bb,
                                            const float* __restrict__ M0, int n_nodes) {
    __shared__ float xs[64][65];
    int lane = threadIdx.x & 63, wid = threadIdx.x >> 6;
    int n = blockIdx.x * 64 + lane;
    bool act = n < n_nodes;
    const int j0 = wid * 16;
    float ov[16];
    if (act) {
        float sn = snorm[n];
        float y[16];
        const float* bj = b + j0;
#pragma unroll
        for (int q = 0; q < 16; ++q) y[q] = bj[q] * sn;
        const float4* g4 = (const float4*)(g + (size_t)n * 64);
        const float* Wj = W + j0;
#pragma unroll
        for (int k4 = 0; k4 < 16; ++k4) {
            float4 xv = g4[k4];
            const float* w0 = Wj + (k4 * 4 + 0) * 64;
            const float* w1 = Wj + (k4 * 4 + 1) * 64;
            const float* w2 = Wj + (k4 * 4 + 2) * 64;
            const float* w3 = Wj + (k4 * 4 + 3) * 64;
#pragma unroll
            for (int q = 0; q < 16; ++q) {
                y[q] = fmaf(xv.x, w0[q], y[q]);
                y[q] = fmaf(xv.y, w1[q], y[q]);
                y[q] = fmaf(xv.z, w2[q], y[q]);
                y[q] = fmaf(xv.w, w3[q], y[q]);
            }
        }
        float nn = norm[n];
        const float* hme = h_in + (size_t)n * 64 + j0;
#pragma unroll
        for (int q = 0; q < 16; ++q) ov[q] = fmaxf(y[q] * nn, 0.f) + hme[q];
        if (h_out) {
            float4* o4 = (float4*)(h_out + (size_t)n * 64 + j0);
#pragma unroll
            for (int q4 = 0; q4 < 4; ++q4) {
                float4 o;
                o.x = ov[q4*4+0]; o.y = ov[q4*4+1]; o.z = ov[q4*4+2]; o.w = ov[q4*4+3];
                o4[q4] = o;
            }
        }
        if (hn_out) {
            uint4* s4 = (uint4*)(hn_out + (size_t)n * 64 + j0);
#pragma unroll
            for (int q8 = 0; q8 < 2; ++q8) {
                uint4 w;
                w.x = (unsigned int)f2bf(ov[q8*8+0] * nn) | ((unsigned int)f2bf(ov[q8*8+1] * nn) << 16);
                w.y = (unsigned int)f2bf(ov[q8*8+2] * nn) | ((unsigned int)f2bf(ov[q8*8+3] * nn) << 16);
                w.z = (unsigned int)f2bf(ov[q8*8+4] * nn) | ((unsigned int)f2bf(ov[q8*8+5] * nn) << 16);
                w.w = (unsigned int)f2bf(ov[q8*8+6] * nn) | ((unsigned int)f2bf(ov[q8*8+7] * nn) << 16);
                s4[q8] = w;
            }
        }
    }
    if (Ab) {
        if (act) {
#pragma unroll
            for (int q = 0; q < 16; ++q) xs[lane][j0 + q] = ov[q];
        }
        __syncthreads();
        if (act) {
            f32x2 ya[8], yb[8];
#pragma unroll
            for (int q = 0; q < 8; ++q) { ya[q][0] = 0.f; ya[q][1] = 0.f; yb[q][0] = 0.f; yb[q][1] = 0.f; }
#pragma unroll
            for (int k = 0; k < 64; ++k) {
                float xk = xs[lane][k];
                f32x2 xk2;
                xk2[0] = xk; xk2[1] = xk;
                const f32x2* wa = (const f32x2*)(M0 + k * 64 + j0);
                const f32x2* wb = (const f32x2*)(M0 + 4096 + k * 64 + j0);
#pragma unroll
                for (int q = 0; q < 8; ++q) {
                    ya[q] = __builtin_elementwise_fma(xk2, wa[q], ya[q]);
                    yb[q] = __builtin_elementwise_fma(xk2, wb[q], yb[q]);
                }
            }
            uint4* pA = (uint4*)(Ab + (size_t)n * 64 + j0);
            uint4* pB = (uint4*)(Bb + (size_t)n * 64 + j0);
            uint4 wa4, wb4;
            wa4.x = pkbf(ya[0]); wa4.y = pkbf(ya[1]); wa4.z = pkbf(ya[2]); wa4.w = pkbf(ya[3]);
            pA[0] = wa4;
            wa4.x = pkbf(ya[4]); wa4.y = pkbf(ya[5]); wa4.z = pkbf(ya[6]); wa4.w = pkbf(ya[7]);
            pA[1] = wa4;
            wb4.x = pkbf(yb[0]); wb4.y = pkbf(yb[1]); wb4.z = pkbf(yb[2]); wb4.w = pkbf(yb[3]);
            pB[0] = wb4;
            wb4.x = pkbf(yb[4]); wb4.y = pkbf(yb[5]); wb4.z = pkbf(yb[6]); wb4.w = pkbf(yb[7]);
            pB[1] = wb4;
        }
    }
}

// ---------------- combo table, embeddings folded on the fly ----------------
// T[(c1*15+c2)*7+p][j] = curr_emb[c1]@M0[128:136] + curr_emb[c2]@M0[136:144]
//                        + pay_emb[p]@M0[144:148] + bM0, all at column j

__global__ void k_tab(const float* __restrict__ curr_emb, const float* __restrict__ pay_emb,
                      const float* __restrict__ M0, const float* __restrict__ bM0,
                      float* __restrict__ T, int total) {
    int idx = blockIdx.x * blockDim.x + threadIdx.x;
    if (idx >= total) return;
    int j = idx & 63, c = idx >> 6;
    int p = c % 7, cc = c / 7;
    int c2 = cc % 15, c1 = cc / 15;
    float s = bM0[j];
#pragma unroll
    for (int k = 0; k < 8; ++k) s = fmaf(curr_emb[c1 * 8 + k], M0[(128 + k) * 64 + j], s);
#pragma unroll
    for (int k = 0; k < 8; ++k) s = fmaf(curr_emb[c2 * 8 + k], M0[(136 + k) * 64 + j], s);
#pragma unroll
    for (int k = 0; k < 4; ++k) s = fmaf(pay_emb[p * 4 + k], M0[(144 + k) * 64 + j], s);
    T[idx] = s;
}

// ---------------- edge MLP — thread-per-edge, packed-f32 math (unchanged from r9) ----------

__global__ __launch_bounds__(256, 2) void k_edge(const unsigned short* __restrict__ Ab,
                                                 const unsigned short* __restrict__ Bb,
                                                 const float* __restrict__ T,
                                                 const float* __restrict__ M0,
                                                 const float* __restrict__ M1,
                                                 const float* __restrict__ bM1,
                                                 const float* __restrict__ M2,
                                                 const float* __restrict__ bM2,
                                                 const int* __restrict__ src,
                                                 const int* __restrict__ dst,
                                                 const int* __restrict__ pc,
                                                 const int* __restrict__ rc,
                                                 const int* __restrict__ pf,
                                                 const float* __restrict__ num,
                                                 float* __restrict__ out, int n_edges) {
    int e = blockIdx.x * blockDim.x + threadIdx.x;
    if (e >= n_edges) return;
    int s = src[e], d = dst[e];
    int combo = (pc[e] * 15 + rc[e]) * 7 + pf[e];
    float nk[5];
#pragma unroll
    for (int k = 0; k < 5; ++k) nk[k] = num[(size_t)e * 5 + k];

    f32x2 x0[32];
    const f32x2* t2 = (const f32x2*)(T + (size_t)combo * 64);
#pragma unroll
    for (int q = 0; q < 32; ++q) x0[q] = t2[q];

    const uint4* ra = (const uint4*)(Ab + (size_t)s * 64);
#pragma unroll
    for (int q = 0; q < 8; ++q) {
        uint4 v = ra[q];
        x0[q*4+0] += bfpair(v.x);
        x0[q*4+1] += bfpair(v.y);
        x0[q*4+2] += bfpair(v.z);
        x0[q*4+3] += bfpair(v.w);
    }
    const uint4* rb = (const uint4*)(Bb + (size_t)d * 64);
#pragma unroll
    for (int q = 0; q < 8; ++q) {
        uint4 v = rb[q];
        x0[q*4+0] += bfpair(v.x);
        x0[q*4+1] += bfpair(v.y);
        x0[q*4+2] += bfpair(v.z);
        x0[q*4+3] += bfpair(v.w);
    }
#pragma unroll
    for (int k = 0; k < 5; ++k) {
        const f32x2* mp = (const f32x2*)(M0 + (148 + k) * 64);
        f32x2 nv;
        nv[0] = nk[k]; nv[1] = nk[k];
#pragma unroll
        for (int q = 0; q < 32; ++q) x0[q] = __builtin_elementwise_fma(nv, mp[q], x0[q]);
    }
    f32x2 zero2;
    zero2[0] = 0.f; zero2[1] = 0.f;
#pragma unroll
    for (int q = 0; q < 32; ++q) x0[q] = __builtin_elementwise_max(x0[q], zero2);

    float lg0 = bM2[0], lg1 = bM2[1];
#pragma unroll
    for (int jh = 0; jh < 2; ++jh) {
        f32x2 x1[16];
        const f32x2* bb = (const f32x2*)(bM1 + jh * 32);
#pragma unroll
        for (int q = 0; q < 16; ++q) x1[q] = bb[q];
#pragma unroll
        for (int k = 0; k < 64; ++k) {
            float xk = x0[k >> 1][k & 1];
            f32x2 xv;
            xv[0] = xk; xv[1] = xk;
            const f32x2* mr = (const f32x2*)(M1 + k * 64 + jh * 32);
#pragma unroll
            for (int q = 0; q < 16; ++q) x1[q] = __builtin_elementwise_fma(xv, mr[q], x1[q]);
        }
#pragma unroll
        for (int q = 0; q < 16; ++q) {
            f32x2 xv = __builtin_elementwise_max(x1[q], zero2);
            int j = jh * 32 + q * 2;
            lg0 = fmaf(xv[0], M2[j * 2 + 0], lg0);
            lg1 = fmaf(xv[0], M2[j * 2 + 1], lg1);
            lg0 = fmaf(xv[1], M2[j * 2 + 2], lg0);
            lg1 = fmaf(xv[1], M2[j * 2 + 3], lg1);
        }
    }
    ((float2*)out)[e] = make_float2(lg0, lg1);
}

// ---------------- launch ----------------

extern "C" void kernel_launch(void* const* d_in, const int* in_sizes, int n_in,
                              void* d_out, int out_size, void* d_ws, size_t ws_size,
                              hipStream_t stream) {
    const float2* node_feats = (const float2*)d_in[0];
    const int*   src  = (const int*)d_in[1];
    const int*   dst  = (const int*)d_in[2];
    const int*   pc   = (const int*)d_in[3];
    const int*   rc   = (const int*)d_in[4];
    const int*   pf   = (const int*)d_in[5];
    const float* num  = (const float*)d_in[6];
    const float* W0   = (const float*)d_in[7];
    const float* b0   = (const float*)d_in[8];
    const float* W1   = (const float*)d_in[9];
    const float* b1   = (const float*)d_in[10];
    const float* W2   = (const float*)d_in[11];
    const float* b2   = (const float*)d_in[12];
    const float* curr_emb = (const float*)d_in[13];
    const float* pay_emb  = (const float*)d_in[14];
    const float* M0   = (const float*)d_in[15];
    const float* bM0  = (const float*)d_in[16];
    const float* M1   = (const float*)d_in[17];
    const float* bM1  = (const float*)d_in[18];
    const float* M2   = (const float*)d_in[19];
    const float* bM2  = (const float*)d_in[20];
    float* out = (float*)d_out;

    char* w = (char*)d_ws;
    auto alloc = [&](size_t bytes) {
        char* p = w;
        w += (bytes + 255) & ~size_t(255);
        return p;
    };
    int*    deg     = (int*)alloc(N_NODES * 4);
    int*    gcount  = (int*)alloc(256);
    float*  norm    = (float*)alloc(N_NODES * 4);
    float*  snorm   = (float*)alloc(N_NODES * 4);
    int*    row_ptr = (int*)alloc((N_NODES + 1) * 4);
    int*    cursor  = (int*)alloc(N_NODES * 4);
    int*    csr_src = (int*)alloc(N_EDGES * 4);
    float*  B1      = (float*)alloc(N_NODES * HID * 4);             // h0
    unsigned short* B2 = (unsigned short*)alloc(N_NODES * HID * 2); // hn (bf16)
    float*  B3      = (float*)alloc(N_NODES * HID * 4);             // g
    float*  B4      = (float*)alloc(N_NODES * HID * 4);             // h1
    unsigned short* Ab = (unsigned short*)alloc(N_NODES * HID * 2);
    unsigned short* Bb = (unsigned short*)alloc(N_NODES * HID * 2);
    float*  T       = (float*)alloc(15 * 15 * 7 * 64 * 4);

    hipMemsetAsync(deg, 0, N_NODES * 4, stream);
    hipMemsetAsync(gcount, 0, 256, stream);
    k_deg<<<(N_EDGES + 255) / 256, 256, 0, stream>>>(dst, deg, N_EDGES);
    k_off<<<(N_NODES + 255) / 256, 256, 0, stream>>>(deg, row_ptr, cursor, norm, gcount, N_NODES);
    k_scatter<<<(N_EDGES + 255) / 256, 256, 0, stream>>>(src, dst, cursor, csr_src, N_EDGES);
    // layer 0 (fused agg + dense, wave per node)
    k_l0<<<(N_NODES + 3) / 4, 256, 0, stream>>>(node_feats, norm, row_ptr, deg, csr_src,
                                                W0, b0, B1, B2, snorm, N_NODES);
    // layer 1
    k_agg<<<(N_NODES + 3) / 4, 256, 0, stream>>>(B2, row_ptr, deg, csr_src, B3, N_NODES);
    k_mv<<<(N_NODES + 63) / 64, 256, 0, stream>>>(B3, B1, W1, b1, norm, snorm,
                                                  B4, B2, nullptr, nullptr, nullptr, N_NODES);
    // layer 2 (+ fused A/B projection via LDS; h2 never hits global)
    k_agg<<<(N_NODES + 3) / 4, 256, 0, stream>>>(B2, row_ptr, deg, csr_src, B3, N_NODES);
    k_mv<<<(N_NODES + 63) / 64, 256, 0, stream>>>(B3, B4, W2, b2, norm, snorm,
                                                  nullptr, nullptr, Ab, Bb, M0, N_NODES);
    // edge path
    k_tab<<<(15 * 15 * 7 * 64 + 255) / 256, 256, 0, stream>>>(curr_emb, pay_emb, M0, bM0,
                                                              T, 15 * 15 * 7 * 64);
    k_edge<<<(N_EDGES + 255) / 256, 256, 0, stream>>>(Ab, Bb, T, M0, M1, bM1, M2, bM2,
                                                      src, dst, pc, rc, pf, num, out, N_EDGES);
}

// Round 11
// 568.922 us; speedup vs baseline: 1.0933x; 1.0030x over previous
//
#include <hip/hip_runtime.h>
#include <hip/hip_bf16.h>

#define N_NODES 50000
#define N_EDGES 800000
#define HID 64

typedef __attribute__((ext_vector_type(2))) float f32x2;

__device__ __forceinline__ unsigned short f2bf(float f) {
    union { float f; unsigned int i; } v;
    v.f = f;
    unsigned int b = v.i;
    return (unsigned short)((b + 0x7FFFu + ((b >> 16) & 1u)) >> 16);
}

__device__ __forceinline__ float bf2f(unsigned short u) {
    union { unsigned int i; float f; } t;
    t.i = ((unsigned int)u) << 16;
    return t.f;
}

// two bf16 packed in a uint -> f32x2
__device__ __forceinline__ f32x2 bfpair(unsigned int u) {
    union { unsigned int i; float f; } lo, hi;
    lo.i = u << 16;
    hi.i = u & 0xFFFF0000u;
    f32x2 r;
    r[0] = lo.f;
    r[1] = hi.f;
    return r;
}

__device__ __forceinline__ unsigned int pkbf(f32x2 v) {
    return (unsigned int)f2bf(v[0]) | ((unsigned int)f2bf(v[1]) << 16);
}

// ---------------- CSR build ----------------

__global__ void k_deg(const int* __restrict__ dst, int* __restrict__ deg, int n) {
    int e = blockIdx.x * blockDim.x + threadIdx.x;
    if (e < n) atomicAdd(&deg[dst[e]], 1);
}

// wave-scan offsets + norm + packed nfn = {nf.x*norm, nf.y*norm, norm, 0}
__global__ void k_off(const int* __restrict__ deg, const float2* __restrict__ nf,
                      int* __restrict__ row_ptr, int* __restrict__ cursor,
                      float* __restrict__ norm, float4* __restrict__ nfn,
                      int* __restrict__ gcount, int n) {
    int i = blockIdx.x * blockDim.x + threadIdx.x;
    int lane = threadIdx.x & 63;
    int v = (i < n) ? deg[i] : 0;
    int s = v;
#pragma unroll
    for (int off = 1; off < 64; off <<= 1) {
        int t = __shfl_up(s, off);
        if (lane >= off) s += t;
    }
    int total = __shfl(s, 63);
    int base = 0;
    if (lane == 63) base = atomicAdd(gcount, total);
    base = __shfl(base, 63);
    int ex = base + s - v;
    if (i < n) {
        row_ptr[i] = ex;
        cursor[i]  = ex;
        float nv = 1.0f / sqrtf(fmaxf((float)v, 1.0f));
        norm[i] = nv;
        float2 f = nf[i];
        nfn[i] = make_float4(f.x * nv, f.y * nv, nv, 0.f);
    }
}

__global__ void k_scatter(const int* __restrict__ src, const int* __restrict__ dst,
                          int* __restrict__ cursor, int* __restrict__ csr_src, int n) {
    int e = blockIdx.x * blockDim.x + threadIdx.x;
    if (e < n) {
        int d = dst[e];
        int pos = atomicAdd(&cursor[d], 1);
        csr_src[pos] = src[e];
    }
}

// ---------------- layer 0 fused: wave per node; single packed gather stream ----------------
// h0 = relu((agg @ W0 + b0*sn) * norm); hn = bf16(h0 * norm)

__global__ __launch_bounds__(256) void k_l0(const float4* __restrict__ nfn,
                                            const float* __restrict__ norm,
                                            const int* __restrict__ row_ptr,
                                            const int* __restrict__ deg,
                                            const int* __restrict__ csr_src,
                                            const float* __restrict__ W0,
                                            const float* __restrict__ b0,
                                            float* __restrict__ h,
                                            unsigned short* __restrict__ hn,
                                            float* __restrict__ snorm, int n_nodes) {
    int lane = threadIdx.x & 63, wid = threadIdx.x >> 6;
    int n = blockIdx.x * 4 + wid;
    if (n >= n_nodes) return;
    int r0 = row_ptr[n], dc = deg[n];
    float a0 = 0.f, a1 = 0.f, sn = 0.f;
    for (int i = lane; i < dc; i += 64) {
        int s = csr_src[r0 + i];
        float4 v = nfn[s];
        a0 += v.x;
        a1 += v.y;
        sn += v.z;
    }
#pragma unroll
    for (int off = 32; off; off >>= 1) {
        a0 += __shfl_xor(a0, off);
        a1 += __shfl_xor(a1, off);
        sn += __shfl_xor(sn, off);
    }
    float nn = norm[n];
    float v = (a0 * W0[lane] + a1 * W0[64 + lane] + b0[lane] * sn) * nn;
    v = fmaxf(v, 0.f);
    h[(size_t)n * 64 + lane] = v;
    hn[(size_t)n * 64 + lane] = f2bf(v * nn);
    if (lane == 0) snorm[n] = sn;
}

// ---------------- aggregation: g[n] = sum_{s in N(n)} hn[s]  (bf16, 8 lanes per row) -------
// lane = (row-group rg = lane>>3, feature-quad fq = lane&7); each VMEM instruction
// fetches 8 rows (8 groups x uint4 = 128B/row). Reduce across groups via shfl_xor.

__global__ __launch_bounds__(256) void k_agg(const unsigned short* __restrict__ hn,
                                             const int* __restrict__ row_ptr,
                                             const int* __restrict__ deg,
                                             const int* __restrict__ csr_src,
                                             float* __restrict__ g, int n_nodes) {
    int lane = threadIdx.x & 63, wid = threadIdx.x >> 6;
    int n = blockIdx.x * 4 + wid;
    if (n >= n_nodes) return;
    const uint4* hn4 = (const uint4*)hn;   // 8 x uint4 per 64-feature row
    int r0 = row_ptr[n], dc = deg[n];
    int rg = lane >> 3;
    int fq = lane & 7;
    f32x2 a0, a1, a2, a3;
    a0[0] = 0.f; a0[1] = 0.f; a1[0] = 0.f; a1[1] = 0.f;
    a2[0] = 0.f; a2[1] = 0.f; a3[0] = 0.f; a3[1] = 0.f;
#pragma unroll 2
    for (int i = 0; i < dc; i += 8) {
        int idx = i + rg;
        if (idx < dc) {
            int s = csr_src[r0 + idx];
            uint4 v = hn4[(size_t)s * 8 + fq];
            a0 += bfpair(v.x);
            a1 += bfpair(v.y);
            a2 += bfpair(v.z);
            a3 += bfpair(v.w);
        }
    }
#pragma unroll
    for (int off = 8; off <= 32; off <<= 1) {
        a0[0] += __shfl_xor(a0[0], off); a0[1] += __shfl_xor(a0[1], off);
        a1[0] += __shfl_xor(a1[0], off); a1[1] += __shfl_xor(a1[1], off);
        a2[0] += __shfl_xor(a2[0], off); a2[1] += __shfl_xor(a2[1], off);
        a3[0] += __shfl_xor(a3[0], off); a3[1] += __shfl_xor(a3[1], off);
    }
    if (rg == 0) {
        float4* gp = (float4*)(g + (size_t)n * 64 + fq * 8);
        gp[0] = make_float4(a0[0], a0[1], a1[0], a1[1]);
        gp[1] = make_float4(a2[0], a2[1], a3[0], a3[1]);
    }
}

// ---------------- dense: h_out = relu((g@W + b*snorm)*norm) + h_in ----------------
// If Ab != null (layer 2): skip global h write; exchange h2 via LDS and emit
// bf16 tables Ab = h2 @ M0[0:64], Bb = h2 @ M0[64:128] instead.

__global__ __launch_bounds__(256) void k_mv(const float* __restrict__ g,
                                            const float* __restrict__ h_in,
                                            const float* __restrict__ W,
                                            const float* __restrict__ b,
                                            const float* __restrict__ norm,
                                            const float* __restrict__ snorm,
                                            float* __restrict__ h_out,
                                            unsigned short* __restrict__ hn_out,
                                            unsigned short* __restrict__ Ab,
                                            unsigned short* __restrict__ Bb,
                                            const float* __restrict__ M0, int n_nodes) {
    __shared__ float xs[64][65];
    int lane = threadIdx.x & 63, wid = threadIdx.x >> 6;
    int n = blockIdx.x * 64 + lane;
    bool act = n < n_nodes;
    const int j0 = wid * 16;
    float ov[16];
    if (act) {
        float sn = snorm[n];
        float y[16];
        const float* bj = b + j0;
#pragma unroll
        for (int q = 0; q < 16; ++q) y[q] = bj[q] * sn;
        const float4* g4 = (const float4*)(g + (size_t)n * 64);
        const float* Wj = W + j0;
#pragma unroll
        for (int k4 = 0; k4 < 16; ++k4) {
            float4 xv = g4[k4];
            const float* w0 = Wj + (k4 * 4 + 0) * 64;
            const float* w1 = Wj + (k4 * 4 + 1) * 64;
            const float* w2 = Wj + (k4 * 4 + 2) * 64;
            const float* w3 = Wj + (k4 * 4 + 3) * 64;
#pragma unroll
            for (int q = 0; q < 16; ++q) {
                y[q] = fmaf(xv.x, w0[q], y[q]);
                y[q] = fmaf(xv.y, w1[q], y[q]);
                y[q] = fmaf(xv.z, w2[q], y[q]);
                y[q] = fmaf(xv.w, w3[q], y[q]);
            }
        }
        float nn = norm[n];
        const float* hme = h_in + (size_t)n * 64 + j0;
#pragma unroll
        for (int q = 0; q < 16; ++q) ov[q] = fmaxf(y[q] * nn, 0.f) + hme[q];
        if (h_out) {
            float4* o4 = (float4*)(h_out + (size_t)n * 64 + j0);
#pragma unroll
            for (int q4 = 0; q4 < 4; ++q4) {
                float4 o;
                o.x = ov[q4*4+0]; o.y = ov[q4*4+1]; o.z = ov[q4*4+2]; o.w = ov[q4*4+3];
                o4[q4] = o;
            }
        }
        if (hn_out) {
            uint4* s4 = (uint4*)(hn_out + (size_t)n * 64 + j0);
            float nn2 = nn;
#pragma unroll
            for (int q8 = 0; q8 < 2; ++q8) {
                uint4 w;
                w.x = (unsigned int)f2bf(ov[q8*8+0] * nn2) | ((unsigned int)f2bf(ov[q8*8+1] * nn2) << 16);
                w.y = (unsigned int)f2bf(ov[q8*8+2] * nn2) | ((unsigned int)f2bf(ov[q8*8+3] * nn2) << 16);
                w.z = (unsigned int)f2bf(ov[q8*8+4] * nn2) | ((unsigned int)f2bf(ov[q8*8+5] * nn2) << 16);
                w.w = (unsigned int)f2bf(ov[q8*8+6] * nn2) | ((unsigned int)f2bf(ov[q8*8+7] * nn2) << 16);
                s4[q8] = w;
            }
        }
    }
    if (Ab) {
        if (act) {
#pragma unroll
            for (int q = 0; q < 16; ++q) xs[lane][j0 + q] = ov[q];
        }
        __syncthreads();
        if (act) {
            f32x2 ya[8], yb[8];
#pragma unroll
            for (int q = 0; q < 8; ++q) { ya[q][0] = 0.f; ya[q][1] = 0.f; yb[q][0] = 0.f; yb[q][1] = 0.f; }
#pragma unroll
            for (int k = 0; k < 64; ++k) {
                float xk = xs[lane][k];
                f32x2 xk2;
                xk2[0] = xk; xk2[1] = xk;
                const f32x2* wa = (const f32x2*)(M0 + k * 64 + j0);
                const f32x2* wb = (const f32x2*)(M0 + 4096 + k * 64 + j0);
#pragma unroll
                for (int q = 0; q < 8; ++q) {
                    ya[q] = __builtin_elementwise_fma(xk2, wa[q], ya[q]);
                    yb[q] = __builtin_elementwise_fma(xk2, wb[q], yb[q]);
                }
            }
            uint4* pA = (uint4*)(Ab + (size_t)n * 64 + j0);
            uint4* pB = (uint4*)(Bb + (size_t)n * 64 + j0);
            uint4 wa4, wb4;
            wa4.x = pkbf(ya[0]); wa4.y = pkbf(ya[1]); wa4.z = pkbf(ya[2]); wa4.w = pkbf(ya[3]);
            pA[0] = wa4;
            wa4.x = pkbf(ya[4]); wa4.y = pkbf(ya[5]); wa4.z = pkbf(ya[6]); wa4.w = pkbf(ya[7]);
            pA[1] = wa4;
            wb4.x = pkbf(yb[0]); wb4.y = pkbf(yb[1]); wb4.z = pkbf(yb[2]); wb4.w = pkbf(yb[3]);
            pB[0] = wb4;
            wb4.x = pkbf(yb[4]); wb4.y = pkbf(yb[5]); wb4.z = pkbf(yb[6]); wb4.w = pkbf(yb[7]);
            pB[1] = wb4;
        }
    }
}

// ---------------- combo table, embeddings folded on the fly ----------------

__global__ void k_tab(const float* __restrict__ curr_emb, const float* __restrict__ pay_emb,
                      const float* __restrict__ M0, const float* __restrict__ bM0,
                      float* __restrict__ T, int total) {
    int idx = blockIdx.x * blockDim.x + threadIdx.x;
    if (idx >= total) return;
    int j = idx & 63, c = idx >> 6;
    int p = c % 7, cc = c / 7;
    int c2 = cc % 15, c1 = cc / 15;
    float s = bM0[j];
#pragma unroll
    for (int k = 0; k < 8; ++k) s = fmaf(curr_emb[c1 * 8 + k], M0[(128 + k) * 64 + j], s);
#pragma unroll
    for (int k = 0; k < 8; ++k) s = fmaf(curr_emb[c2 * 8 + k], M0[(136 + k) * 64 + j], s);
#pragma unroll
    for (int k = 0; k < 4; ++k) s = fmaf(pay_emb[p * 4 + k], M0[(144 + k) * 64 + j], s);
    T[idx] = s;
}

// ---------------- edge MLP — thread-per-edge, packed-f32 math (byte-identical to r10) ------

__global__ __launch_bounds__(256, 2) void k_edge(const unsigned short* __restrict__ Ab,
                                                 const unsigned short* __restrict__ Bb,
                                                 const float* __restrict__ T,
                                                 const float* __restrict__ M0,
                                                 const float* __restrict__ M1,
                                                 const float* __restrict__ bM1,
                                                 const float* __restrict__ M2,
                                                 const float* __restrict__ bM2,
                                                 const int* __restrict__ src,
                                                 const int* __restrict__ dst,
                                                 const int* __restrict__ pc,
                                                 const int* __restrict__ rc,
                                                 const int* __restrict__ pf,
                                                 const float* __restrict__ num,
                                                 float* __restrict__ out, int n_edges) {
    int e = blockIdx.x * blockDim.x + threadIdx.x;
    if (e >= n_edges) return;
    int s = src[e], d = dst[e];
    int combo = (pc[e] * 15 + rc[e]) * 7 + pf[e];
    float nk[5];
#pragma unroll
    for (int k = 0; k < 5; ++k) nk[k] = num[(size_t)e * 5 + k];

    f32x2 x0[32];
    const f32x2* t2 = (const f32x2*)(T + (size_t)combo * 64);
#pragma unroll
    for (int q = 0; q < 32; ++q) x0[q] = t2[q];

    const uint4* ra = (const uint4*)(Ab + (size_t)s * 64);
#pragma unroll
    for (int q = 0; q < 8; ++q) {
        uint4 v = ra[q];
        x0[q*4+0] += bfpair(v.x);
        x0[q*4+1] += bfpair(v.y);
        x0[q*4+2] += bfpair(v.z);
        x0[q*4+3] += bfpair(v.w);
    }
    const uint4* rb = (const uint4*)(Bb + (size_t)d * 64);
#pragma unroll
    for (int q = 0; q < 8; ++q) {
        uint4 v = rb[q];
        x0[q*4+0] += bfpair(v.x);
        x0[q*4+1] += bfpair(v.y);
        x0[q*4+2] += bfpair(v.z);
        x0[q*4+3] += bfpair(v.w);
    }
#pragma unroll
    for (int k = 0; k < 5; ++k) {
        const f32x2* mp = (const f32x2*)(M0 + (148 + k) * 64);
        f32x2 nv;
        nv[0] = nk[k]; nv[1] = nk[k];
#pragma unroll
        for (int q = 0; q < 32; ++q) x0[q] = __builtin_elementwise_fma(nv, mp[q], x0[q]);
    }
    f32x2 zero2;
    zero2[0] = 0.f; zero2[1] = 0.f;
#pragma unroll
    for (int q = 0; q < 32; ++q) x0[q] = __builtin_elementwise_max(x0[q], zero2);

    float lg0 = bM2[0], lg1 = bM2[1];
#pragma unroll
    for (int jh = 0; jh < 2; ++jh) {
        f32x2 x1[16];
        const f32x2* bb = (const f32x2*)(bM1 + jh * 32);
#pragma unroll
        for (int q = 0; q < 16; ++q) x1[q] = bb[q];
#pragma unroll
        for (int k = 0; k < 64; ++k) {
            float xk = x0[k >> 1][k & 1];
            f32x2 xv;
            xv[0] = xk; xv[1] = xk;
            const f32x2* mr = (const f32x2*)(M1 + k * 64 + jh * 32);
#pragma unroll
            for (int q = 0; q < 16; ++q) x1[q] = __builtin_elementwise_fma(xv, mr[q], x1[q]);
        }
#pragma unroll
        for (int q = 0; q < 16; ++q) {
            f32x2 xv = __builtin_elementwise_max(x1[q], zero2);
            int j = jh * 32 + q * 2;
            lg0 = fmaf(xv[0], M2[j * 2 + 0], lg0);
            lg1 = fmaf(xv[0], M2[j * 2 + 1], lg1);
            lg0 = fmaf(xv[1], M2[j * 2 + 2], lg0);
            lg1 = fmaf(xv[1], M2[j * 2 + 3], lg1);
        }
    }
    ((float2*)out)[e] = make_float2(lg0, lg1);
}

// ---------------- launch ----------------

extern "C" void kernel_launch(void* const* d_in, const int* in_sizes, int n_in,
                              void* d_out, int out_size, void* d_ws, size_t ws_size,
                              hipStream_t stream) {
    const float2* node_feats = (const float2*)d_in[0];
    const int*   src  = (const int*)d_in[1];
    const int*   dst  = (const int*)d_in[2];
    const int*   pc   = (const int*)d_in[3];
    const int*   rc   = (const int*)d_in[4];
    const int*   pf   = (const int*)d_in[5];
    const float* num  = (const float*)d_in[6];
    const float* W0   = (const float*)d_in[7];
    const float* b0   = (const float*)d_in[8];
    const float* W1   = (const float*)d_in[9];
    const float* b1   = (const float*)d_in[10];
    const float* W2   = (const float*)d_in[11];
    const float* b2   = (const float*)d_in[12];
    const float* curr_emb = (const float*)d_in[13];
    const float* pay_emb  = (const float*)d_in[14];
    const float* M0   = (const float*)d_in[15];
    const float* bM0  = (const float*)d_in[16];
    const float* M1   = (const float*)d_in[17];
    const float* bM1  = (const float*)d_in[18];
    const float* M2   = (const float*)d_in[19];
    const float* bM2  = (const float*)d_in[20];
    float* out = (float*)d_out;

    char* w = (char*)d_ws;
    auto alloc = [&](size_t bytes) {
        char* p = w;
        w += (bytes + 255) & ~size_t(255);
        return p;
    };
    int*    deg     = (int*)alloc(N_NODES * 4);
    int*    gcount  = (int*)alloc(256);
    float*  norm    = (float*)alloc(N_NODES * 4);
    float*  snorm   = (float*)alloc(N_NODES * 4);
    float4* nfn     = (float4*)alloc(N_NODES * 16);
    int*    row_ptr = (int*)alloc((N_NODES + 1) * 4);
    int*    cursor  = (int*)alloc(N_NODES * 4);
    int*    csr_src = (int*)alloc(N_EDGES * 4);
    float*  B1      = (float*)alloc(N_NODES * HID * 4);             // h0
    unsigned short* B2 = (unsigned short*)alloc(N_NODES * HID * 2); // hn (bf16)
    float*  B3      = (float*)alloc(N_NODES * HID * 4);             // g
    float*  B4      = (float*)alloc(N_NODES * HID * 4);             // h1
    unsigned short* Ab = (unsigned short*)alloc(N_NODES * HID * 2);
    unsigned short* Bb = (unsigned short*)alloc(N_NODES * HID * 2);
    float*  T       = (float*)alloc(15 * 15 * 7 * 64 * 4);

    hipMemsetAsync(deg, 0, N_NODES * 4, stream);
    hipMemsetAsync(gcount, 0, 256, stream);
    k_deg<<<(N_EDGES + 255) / 256, 256, 0, stream>>>(dst, deg, N_EDGES);
    k_off<<<(N_NODES + 255) / 256, 256, 0, stream>>>(deg, node_feats, row_ptr, cursor,
                                                     norm, nfn, gcount, N_NODES);
    k_scatter<<<(N_EDGES + 255) / 256, 256, 0, stream>>>(src, dst, cursor, csr_src, N_EDGES);
    // layer 0 (fused agg + dense, wave per node)
    k_l0<<<(N_NODES + 3) / 4, 256, 0, stream>>>(nfn, norm, row_ptr, deg, csr_src,
                                                W0, b0, B1, B2, snorm, N_NODES);
    // layer 1
    k_agg<<<(N_NODES + 3) / 4, 256, 0, stream>>>(B2, row_ptr, deg, csr_src, B3, N_NODES);
    k_mv<<<(N_NODES + 63) / 64, 256, 0, stream>>>(B3, B1, W1, b1, norm, snorm,
                                                  B4, B2, nullptr, nullptr, nullptr, N_NODES);
    // layer 2 (+ fused A/B projection via LDS; h2 never hits global)
    k_agg<<<(N_NODES + 3) / 4, 256, 0, stream>>>(B2, row_ptr, deg, csr_src, B3, N_NODES);
    k_mv<<<(N_NODES + 63) / 64, 256, 0, stream>>>(B3, B4, W2, b2, norm, snorm,
                                                  nullptr, nullptr, Ab, Bb, M0, N_NODES);
    // edge path
    k_tab<<<(15 * 15 * 7 * 64 + 255) / 256, 256, 0, stream>>>(curr_emb, pay_emb, M0, bM0,
                                                              T, 15 * 15 * 7 * 64);
    k_edge<<<(N_EDGES + 255) / 256, 256, 0, stream>>>(Ab, Bb, T, M0, M1, bM1, M2, bM2,
                                                      src, dst, pc, rc, pf, num, out, N_EDGES);
}